// Round 13
// baseline (835.337 us; speedup 1.0000x reference)
//
#include <hip/hip_runtime.h>
#include <math.h>

#define TOT (256*64*64)          // 1048576
#define EPS_SINK 1e-8f
#define THR (1.0f/64.0f)
#define INV_BSCALE 0.5412658773652741f   // 1/sqrt(2+sqrt(2))
#define UNTANH_A 0.6f

typedef float nativef4 __attribute__((ext_vector_type(4)));

static __device__ __forceinline__ float buntanh(float x) {
    return (tanhf(x) + UNTANH_A * x) * INV_BSCALE;
}

#if __has_builtin(__builtin_amdgcn_rcpf)
static __device__ __forceinline__ float fastrcp(float x) {
    return __builtin_amdgcn_rcpf(x);
}
#else
static __device__ __forceinline__ float fastrcp(float x) { return 1.0f / x; }
#endif

// ---------------------------------------------------------------------------
// Ticket kernel: grid 1024 x 512 threads (4 blocks/CU -> 32 waves/CU, 2x the
// fused version's occupancy for the memory phase).
// Producer: block beta covers b = beta>>2, quarter q = beta&3 -> 48 gemvs
//   (r3-proven pattern: NT dwordx4, xor16/32 reduce), QKV -> GLOBAL.
// Ticket: __syncthreads + threadfence + atomicAdd(cnt[b]); the 4th finisher
//   runs attn+sinkhorn+loss for all 16 heads (2 per wave, r7-proven wave-local
//   code, QKV from L2-hot global). Hidden behind other blocks' streaming for
//   all but the last b. Deterministic output regardless of executor; no
//   spin-waits -> no dispatch-order deadlock; cnt zeroed per launch.
// ---------------------------------------------------------------------------
__global__ __launch_bounds__(512, 8) void brain_ticket_kernel(
    const float* __restrict__ env, const float* __restrict__ state,
    const float* __restrict__ w1, const float* __restrict__ w2,
    const float* __restrict__ w3,
    float* __restrict__ pred, float* __restrict__ keys,
    float* __restrict__ quer, float* __restrict__ part,
    int* __restrict__ cnt)
{
    __shared__ int oldc;
    __shared__ float redL[8][3];

    const int beta = blockIdx.x;
    const int b    = beta >> 2;
    const int q    = beta & 3;
    const int wave = threadIdx.x >> 6;   // 0..7
    const int l    = threadIdx.x & 63;
    const int k4   = l & 15;
    const int jg   = l >> 4;

    // ---- producer: 6 gemvs per wave (48 per block) ----
#pragma unroll 2
    for (int tt = 0; tt < 6; ++tt) {
        const int t    = q * 48 + wave * 6 + tt;   // 0..191
        const int widx = t >> 6;                   // 0,1,2
        const int n    = t & 63;
        const float* __restrict__ w =
            (widx == 0) ? w1 : (widx == 1) ? w2 : w3;
        float* __restrict__ outp =
            (widx == 0) ? pred : (widx == 1) ? keys : quer;
        const size_t bn = (size_t)(b * 64 + n);

        const float* sp = state + bn * 64 + jg * 16;
        float s[16];
#pragma unroll
        for (int i = 0; i < 4; ++i) {
            const float4 v = *(const float4*)(sp + 4 * i);
            s[4 * i + 0] = v.x; s[4 * i + 1] = v.y;
            s[4 * i + 2] = v.z; s[4 * i + 3] = v.w;
        }

        const nativef4* wp = (const nativef4*)(w + bn * 4096 +
                                               (size_t)(jg * 16) * 64 + k4 * 4);
        float a0 = 0.f, a1 = 0.f, a2 = 0.f, a3 = 0.f;
#pragma unroll
        for (int jj = 0; jj < 16; ++jj) {
            const nativef4 wv = __builtin_nontemporal_load(wp + jj * 16);
            a0 = fmaf(s[jj], wv.x, a0);
            a1 = fmaf(s[jj], wv.y, a1);
            a2 = fmaf(s[jj], wv.z, a2);
            a3 = fmaf(s[jj], wv.w, a3);
        }
        a0 += __shfl_xor(a0, 16, 64); a0 += __shfl_xor(a0, 32, 64);
        a1 += __shfl_xor(a1, 16, 64); a1 += __shfl_xor(a1, 32, 64);
        a2 += __shfl_xor(a2, 16, 64); a2 += __shfl_xor(a2, 32, 64);
        a3 += __shfl_xor(a3, 16, 64); a3 += __shfl_xor(a3, 32, 64);
        if (jg == 0) {
            float4 o4;
            o4.x = buntanh(a0);
            o4.y = buntanh(a1);
            o4.z = buntanh(a2);
            o4.w = buntanh(a3);
            *(float4*)(outp + bn * 64 + k4 * 4) = o4;
        }
    }

    // ---- ticket ----
    __syncthreads();
    if (threadIdx.x == 0) {
        __threadfence();                       // release QKV stores
        oldc = atomicAdd(&cnt[b], 1);
    }
    __syncthreads();
    if (oldc != 3) return;
    __threadfence();                           // acquire: invalidate stale L2

    // ---- epilogue: attn + sinkhorn + loss, 2 heads per wave ----
    const int rg = l >> 3;                     // rows 8rg..+7
    const int cg = l & 7;                      // cols 8cg..+7
    float l1 = 0.f, l2 = 0.f, l3 = 0.f;

    for (int hh = 0; hh < 2; ++hh) {
        const int h = wave * 2 + hh;           // 0..15
        const size_t base = (size_t)(b * 64) * 64 + h * 4;

        float p[8][8];
        float ss = 0.f, mx = -1e30f;
        {
            float4 qf[8], kf[8];
#pragma unroll
            for (int i = 0; i < 8; ++i)
                qf[i] = *(const float4*)(quer + base + (size_t)(8 * rg + i) * 64);
#pragma unroll
            for (int j = 0; j < 8; ++j)
                kf[j] = *(const float4*)(keys + base + (size_t)(8 * cg + j) * 64);
#pragma unroll
            for (int i = 0; i < 8; ++i) {
#pragma unroll
                for (int j = 0; j < 8; ++j) {
                    float e = (qf[i].x * kf[j].x + qf[i].y * kf[j].y +
                               qf[i].z * kf[j].z + qf[i].w * kf[j].w) * 0.5f;
                    p[i][j] = e;
                    ss += e * e;
                    mx = fmaxf(mx, e);
                }
            }
        }
#pragma unroll
        for (int o = 1; o <= 32; o <<= 1) {
            ss += __shfl_xor(ss, o, 64);
            mx = fmaxf(mx, __shfl_xor(mx, o, 64));
        }
        const float scale = rsqrtf(ss * (1.0f / 4096.0f) + 1e-6f);

#pragma unroll
        for (int i = 0; i < 8; ++i)
#pragma unroll
            for (int j = 0; j < 8; ++j)
                p[i][j] = __expf(scale * (p[i][j] - mx));

        for (int it = 0; it < 10; ++it) {
#pragma unroll
            for (int i = 0; i < 8; ++i) {
                float r = ((p[i][0] + p[i][1]) + (p[i][2] + p[i][3])) +
                          ((p[i][4] + p[i][5]) + (p[i][6] + p[i][7]));
                r += __shfl_xor(r, 1, 64);
                r += __shfl_xor(r, 2, 64);
                r += __shfl_xor(r, 4, 64);
                const float inv = fastrcp(r + EPS_SINK);
#pragma unroll
                for (int j = 0; j < 8; ++j) p[i][j] *= inv;
            }
#pragma unroll
            for (int j = 0; j < 8; ++j) {
                float c = ((p[0][j] + p[1][j]) + (p[2][j] + p[3][j])) +
                          ((p[4][j] + p[5][j]) + (p[6][j] + p[7][j]));
                c += __shfl_xor(c, 8, 64);
                c += __shfl_xor(c, 16, 64);
                c += __shfl_xor(c, 32, 64);
                const float inv = fastrcp(c + EPS_SINK);
#pragma unroll
                for (int i = 0; i < 8; ++i) p[i][j] *= inv;
            }
        }

#pragma unroll
        for (int i = 0; i < 8; ++i)
#pragma unroll
            for (int j = 0; j < 8; ++j)
                p[i][j] = (p[i][j] > THR) ? p[i][j] : 0.f;

        // A@V partials over own cols, butterfly over cg
        float o8[8][4];
        {
            float4 vf[8];
#pragma unroll
            for (int j = 0; j < 8; ++j)
                vf[j] = *(const float4*)(pred + base + (size_t)(8 * cg + j) * 64);
#pragma unroll
            for (int i = 0; i < 8; ++i) {
                float d0 = 0.f, d1 = 0.f, d2 = 0.f, d3 = 0.f;
#pragma unroll
                for (int j = 0; j < 8; ++j) {
                    d0 = fmaf(p[i][j], vf[j].x, d0);
                    d1 = fmaf(p[i][j], vf[j].y, d1);
                    d2 = fmaf(p[i][j], vf[j].z, d2);
                    d3 = fmaf(p[i][j], vf[j].w, d3);
                }
                o8[i][0] = d0; o8[i][1] = d1; o8[i][2] = d2; o8[i][3] = d3;
            }
        }
#pragma unroll
        for (int i = 0; i < 8; ++i)
#pragma unroll
            for (int d = 0; d < 4; ++d) {
                float v = o8[i][d];
                v += __shfl_xor(v, 1, 64);
                v += __shfl_xor(v, 2, 64);
                v += __shfl_xor(v, 4, 64);
                o8[i][d] = v;
            }

        // static select of row i == cg
        float tva0 = o8[0][0], tva1 = o8[0][1], tva2 = o8[0][2], tva3 = o8[0][3];
#pragma unroll
        for (int i = 1; i < 8; ++i) {
            if (cg == i) {
                tva0 = o8[i][0]; tva1 = o8[i][1];
                tva2 = o8[i][2]; tva3 = o8[i][3];
            }
        }

        // loss for row n = 8rg+cg, cols h*4..+3
        {
            const int n = 8 * rg + cg;
            const float4 pv = *(const float4*)(pred + base + (size_t)n * 64);
            const float4 kv = *(const float4*)(keys + base + (size_t)n * 64);
            const float4 qv = *(const float4*)(quer + base + (size_t)n * 64);
            const float4 sv = *(const float4*)(state + base + (size_t)n * 64);
            float pa[4] = {pv.x, pv.y, pv.z, pv.w};
            float ka[4] = {kv.x, kv.y, kv.z, kv.w};
            float qa[4] = {qv.x, qv.y, qv.z, qv.w};
            float sa[4] = {sv.x, sv.y, sv.z, sv.w};
#pragma unroll
            for (int d = 0; d < 4; ++d) {
                float tv;
                if (n < 2) {
                    const int idx = n * 64 + h * 4 + d;
                    tv = (idx < 100) ? env[b * 100 + idx] : 0.f;
                } else {
                    tv = (d == 0) ? tva0 : (d == 1) ? tva1
                       : (d == 2) ? tva2 : tva3;
                }
                const float d1 = pa[d] - tv;
                const float d2 = ka[d] - sa[d];
                const float d3 = qa[d] - tv;
                l1 = fmaf(d1, d1, l1);
                l2 = fmaf(d2, d2, l2);
                l3 = fmaf(d3, d3, l3);
            }
        }
    }

#pragma unroll
    for (int o = 1; o <= 32; o <<= 1) {
        l1 += __shfl_xor(l1, o, 64);
        l2 += __shfl_xor(l2, o, 64);
        l3 += __shfl_xor(l3, o, 64);
    }
    if (l == 0) { redL[wave][0] = l1; redL[wave][1] = l2; redL[wave][2] = l3; }
    __syncthreads();
    if (threadIdx.x == 0) {
        float s1 = 0.f, s2 = 0.f, s3 = 0.f;
#pragma unroll
        for (int wv = 0; wv < 8; ++wv) {
            s1 += redL[wv][0]; s2 += redL[wv][1]; s3 += redL[wv][2];
        }
        part[b]       = s1;
        part[256 + b] = s2;
        part[512 + b] = s3;
    }
}

// ---------------------------------------------------------------------------
// Final reduce -> scalar loss
// ---------------------------------------------------------------------------
__global__ __launch_bounds__(256) void loss_final_kernel(
    const float* __restrict__ part, float* __restrict__ out)
{
    float a = 0.f;
    for (int i = threadIdx.x; i < 768; i += 256) a += part[i];
#pragma unroll
    for (int o = 32; o >= 1; o >>= 1) a += __shfl_xor(a, o, 64);
    __shared__ float red[4];
    const int wv = threadIdx.x >> 6, ln = threadIdx.x & 63;
    if (ln == 0) red[wv] = a;
    __syncthreads();
    if (threadIdx.x == 0) {
        out[0] = (red[0] + red[1] + red[2] + red[3]) * (1.0f / (float)TOT);
    }
}

extern "C" void kernel_launch(void* const* d_in, const int* in_sizes, int n_in,
                              void* d_out, int out_size, void* d_ws, size_t ws_size,
                              hipStream_t stream)
{
    const float* env   = (const float*)d_in[0];
    const float* state = (const float*)d_in[1];
    const float* w1    = (const float*)d_in[2];
    const float* w2    = (const float*)d_in[3];
    const float* w3    = (const float*)d_in[4];
    float* out = (float*)d_out;

    float* wsf  = (float*)d_ws;
    float* pred = wsf;
    float* keys = wsf + 1 * TOT;
    float* quer = wsf + 2 * TOT;
    float* part = wsf + 3 * TOT;          // 768 floats
    int*   cnt  = (int*)(wsf + 3 * TOT + 768);  // 256 ints

    hipMemsetAsync(cnt, 0, 256 * sizeof(int), stream);
    hipLaunchKernelGGL(brain_ticket_kernel, dim3(1024), dim3(512), 0, stream,
                       env, state, w1, w2, w3, pred, keys, quer, part, cnt);
    hipLaunchKernelGGL(loss_final_kernel, dim3(1), dim3(256), 0, stream,
                       part, out);
}

// Round 14
// 152.827 us; speedup vs baseline: 5.4659x; 5.4659x over previous
//
#include <hip/hip_runtime.h>
#include <math.h>

#define TOT (256*64*64)          // 1048576
#define EPS_SINK 1e-8f
#define THR (1.0f/64.0f)
#define INV_BSCALE 0.5412658773652741f   // 1/sqrt(2+sqrt(2))
#define UNTANH_A 0.6f

typedef float nativef4 __attribute__((ext_vector_type(4)));

static __device__ __forceinline__ float buntanh(float x) {
    return (tanhf(x) + UNTANH_A * x) * INV_BSCALE;
}

#if __has_builtin(__builtin_amdgcn_rcpf)
static __device__ __forceinline__ float fastrcp(float x) {
    return __builtin_amdgcn_rcpf(x);
}
#else
static __device__ __forceinline__ float fastrcp(float x) { return 1.0f / x; }
#endif

// ---------------------------------------------------------------------------
// Fused kernel v6: one block per b, 1024 threads = 16 waves. Deferred-V
// overlap schedule:
//   phase A : all 16 waves stream K,Q (128 tasks, 8/wave)     ~102 us
//   barrier
//   window  : waves 12..15 stream V (64 tasks, 16/wave)       ~51 us
//             waves 0..11 attn part-1 (QK^T..sinkhorn..thr)    hidden
//   barrier
//   tail    : waves 12..15 attn part-1 for heads 12..15        ~4 us
//             all waves: A@V + fused loss for own head
// Arithmetic identical to r11 (proven); only scheduling differs.
// ---------------------------------------------------------------------------
__global__ __launch_bounds__(1024, 4) void fused_brain_kernel(
    const float* __restrict__ env, const float* __restrict__ state,
    const float* __restrict__ w1, const float* __restrict__ w2,
    const float* __restrict__ w3, float* __restrict__ part)
{
    __shared__ float Vh[64][65];     // pred
    __shared__ float Kh[64][65];     // keys
    __shared__ float Qh[64][65];     // queries
    __shared__ float redL[16][3];

    const int b    = blockIdx.x;
    const int wave = threadIdx.x >> 6;   // 0..15
    const int l    = threadIdx.x & 63;
    const int k4   = l & 15;
    const int jg   = l >> 4;
    const int rg   = l >> 3;             // attn rows 8rg..+7
    const int cg   = l & 7;              // attn cols 8cg..+7

    // r3/r9-proven gemv task: NT dwordx4, xor16+32 reduce, buntanh -> LDS
    auto gemv_task = [&](const float* __restrict__ w, float (*dst)[65],
                         const int n) {
        const size_t bn = (size_t)(b * 64 + n);
        const float* sp = state + bn * 64 + jg * 16;
        float s[16];
#pragma unroll
        for (int i = 0; i < 4; ++i) {
            const float4 v = *(const float4*)(sp + 4 * i);
            s[4 * i + 0] = v.x; s[4 * i + 1] = v.y;
            s[4 * i + 2] = v.z; s[4 * i + 3] = v.w;
        }
        const nativef4* wp = (const nativef4*)(w + bn * 4096 +
                                               (size_t)(jg * 16) * 64 + k4 * 4);
        float a0 = 0.f, a1 = 0.f, a2 = 0.f, a3 = 0.f;
#pragma unroll
        for (int jj = 0; jj < 16; ++jj) {
            const nativef4 wv = __builtin_nontemporal_load(wp + jj * 16);
            a0 = fmaf(s[jj], wv.x, a0);
            a1 = fmaf(s[jj], wv.y, a1);
            a2 = fmaf(s[jj], wv.z, a2);
            a3 = fmaf(s[jj], wv.w, a3);
        }
        a0 += __shfl_xor(a0, 16, 64); a0 += __shfl_xor(a0, 32, 64);
        a1 += __shfl_xor(a1, 16, 64); a1 += __shfl_xor(a1, 32, 64);
        a2 += __shfl_xor(a2, 16, 64); a2 += __shfl_xor(a2, 32, 64);
        a3 += __shfl_xor(a3, 16, 64); a3 += __shfl_xor(a3, 32, 64);
        if (jg == 0) {
            dst[n][4 * k4 + 0] = buntanh(a0);
            dst[n][4 * k4 + 1] = buntanh(a1);
            dst[n][4 * k4 + 2] = buntanh(a2);
            dst[n][4 * k4 + 3] = buntanh(a3);
        }
    };

    float p[8][8];   // per-lane 8x8 subtile of this wave's head

    // attn part-1: QK^T -> rmsnorm scale -> exp -> sinkhorn(10) -> threshold
    auto attn_part1 = [&](const int h) {
        const int cb = 4 * h;
        float ss = 0.f, mx = -1e30f;
        {
            float kq[8][4];
#pragma unroll
            for (int j = 0; j < 8; ++j)
#pragma unroll
                for (int d = 0; d < 4; ++d)
                    kq[j][d] = Kh[8 * cg + j][cb + d];
#pragma unroll
            for (int i = 0; i < 8; ++i) {
                const float q0 = Qh[8 * rg + i][cb + 0];
                const float q1 = Qh[8 * rg + i][cb + 1];
                const float q2 = Qh[8 * rg + i][cb + 2];
                const float q3 = Qh[8 * rg + i][cb + 3];
#pragma unroll
                for (int j = 0; j < 8; ++j) {
                    const float e = (q0 * kq[j][0] + q1 * kq[j][1] +
                                     q2 * kq[j][2] + q3 * kq[j][3]) * 0.5f;
                    p[i][j] = e;
                    ss += e * e;
                    mx = fmaxf(mx, e);
                }
            }
        }
#pragma unroll
        for (int o = 1; o <= 32; o <<= 1) {
            ss += __shfl_xor(ss, o, 64);
            mx = fmaxf(mx, __shfl_xor(mx, o, 64));
        }
        const float scale = rsqrtf(ss * (1.0f / 4096.0f) + 1e-6f);

#pragma unroll
        for (int i = 0; i < 8; ++i)
#pragma unroll
            for (int j = 0; j < 8; ++j)
                p[i][j] = __expf(scale * (p[i][j] - mx));

        for (int it = 0; it < 10; ++it) {
#pragma unroll
            for (int i = 0; i < 8; ++i) {
                float r = ((p[i][0] + p[i][1]) + (p[i][2] + p[i][3])) +
                          ((p[i][4] + p[i][5]) + (p[i][6] + p[i][7]));
                r += __shfl_xor(r, 1, 64);
                r += __shfl_xor(r, 2, 64);
                r += __shfl_xor(r, 4, 64);
                const float inv = fastrcp(r + EPS_SINK);
#pragma unroll
                for (int j = 0; j < 8; ++j) p[i][j] *= inv;
            }
#pragma unroll
            for (int j = 0; j < 8; ++j) {
                float c = ((p[0][j] + p[1][j]) + (p[2][j] + p[3][j])) +
                          ((p[4][j] + p[5][j]) + (p[6][j] + p[7][j]));
                c += __shfl_xor(c, 8, 64);
                c += __shfl_xor(c, 16, 64);
                c += __shfl_xor(c, 32, 64);
                const float inv = fastrcp(c + EPS_SINK);
#pragma unroll
                for (int i = 0; i < 8; ++i) p[i][j] *= inv;
            }
        }

#pragma unroll
        for (int i = 0; i < 8; ++i)
#pragma unroll
            for (int j = 0; j < 8; ++j)
                p[i][j] = (p[i][j] > THR) ? p[i][j] : 0.f;
    };

    // ---- phase A: stream K (w2) and Q (w3): tasks 64..191, 8 per wave ----
#pragma unroll 2
    for (int tt = 0; tt < 8; ++tt) {
        const int task = 64 + wave * 8 + tt;
        const int widx = task >> 6;           // 1 or 2
        const int n    = task & 63;
        gemv_task(widx == 1 ? w2 : w3, widx == 1 ? Kh : Qh, n);
    }
    __syncthreads();                          // Kh, Qh ready

    // ---- window: V streaming (waves 12..15) || attn part-1 (waves 0..11) ----
    if (wave >= 12) {
#pragma unroll 2
        for (int tt = 0; tt < 16; ++tt) {
            gemv_task(w1, Vh, (wave - 12) * 16 + tt);
        }
    } else {
        attn_part1(wave);
    }
    __syncthreads();                          // Vh ready; waves 0..11 have P

    // ---- tail: late heads' part-1 on waves 12..15 ----
    if (wave >= 12) attn_part1(wave);

    // ---- A@V in two groups of 4 rows (r11-proven) + static select ----
    const int cb = 4 * wave;
    float tva0 = 0.f, tva1 = 0.f, tva2 = 0.f, tva3 = 0.f;
#pragma unroll
    for (int grp = 0; grp < 2; ++grp) {
        float og[4][4];
#pragma unroll
        for (int i = 0; i < 4; ++i)
#pragma unroll
            for (int d = 0; d < 4; ++d) og[i][d] = 0.f;

#pragma unroll
        for (int jh = 0; jh < 8; jh += 4) {
            float vf[4][4];
#pragma unroll
            for (int j = 0; j < 4; ++j)
#pragma unroll
                for (int d = 0; d < 4; ++d)
                    vf[j][d] = Vh[8 * cg + jh + j][cb + d];
#pragma unroll
            for (int i = 0; i < 4; ++i)
#pragma unroll
                for (int j = 0; j < 4; ++j) {
                    og[i][0] = fmaf(p[4 * grp + i][jh + j], vf[j][0], og[i][0]);
                    og[i][1] = fmaf(p[4 * grp + i][jh + j], vf[j][1], og[i][1]);
                    og[i][2] = fmaf(p[4 * grp + i][jh + j], vf[j][2], og[i][2]);
                    og[i][3] = fmaf(p[4 * grp + i][jh + j], vf[j][3], og[i][3]);
                }
        }
#pragma unroll
        for (int i = 0; i < 4; ++i)
#pragma unroll
            for (int d = 0; d < 4; ++d) {
                float v = og[i][d];
                v += __shfl_xor(v, 1, 64);
                v += __shfl_xor(v, 2, 64);
                v += __shfl_xor(v, 4, 64);
                og[i][d] = v;
            }
        if ((cg >> 2) == grp) {
#pragma unroll
            for (int i = 0; i < 4; ++i) {
                if ((cg & 3) == i) {
                    tva0 = og[i][0]; tva1 = og[i][1];
                    tva2 = og[i][2]; tva3 = og[i][3];
                }
            }
        }
    }

    // ---- fused loss for row n = 8rg+cg, cols cb..cb+3 ----
    float l1 = 0.f, l2 = 0.f, l3 = 0.f;
    {
        const int n = 8 * rg + cg;
        const float* srow = state + ((size_t)(b * 64 + n)) * 64;
#pragma unroll
        for (int d = 0; d < 4; ++d) {
            const int c = cb + d;
            float tv;
            if (n < 2) {
                const int idx = n * 64 + c;
                tv = (idx < 100) ? env[b * 100 + idx] : 0.f;
            } else {
                tv = (d == 0) ? tva0 : (d == 1) ? tva1 : (d == 2) ? tva2 : tva3;
            }
            const float pv = Vh[n][c];
            const float kk = Kh[n][c];
            const float qv = Qh[n][c];
            const float sv = srow[c];
            const float d1 = pv - tv;
            const float d2 = kk - sv;
            const float d3 = qv - tv;
            l1 = fmaf(d1, d1, l1);
            l2 = fmaf(d2, d2, l2);
            l3 = fmaf(d3, d3, l3);
        }
    }
#pragma unroll
    for (int o = 1; o <= 32; o <<= 1) {
        l1 += __shfl_xor(l1, o, 64);
        l2 += __shfl_xor(l2, o, 64);
        l3 += __shfl_xor(l3, o, 64);
    }
    if (l == 0) { redL[wave][0] = l1; redL[wave][1] = l2; redL[wave][2] = l3; }
    __syncthreads();
    if (threadIdx.x == 0) {
        float s1 = 0.f, s2 = 0.f, s3 = 0.f;
#pragma unroll
        for (int wv = 0; wv < 16; ++wv) {
            s1 += redL[wv][0]; s2 += redL[wv][1]; s3 += redL[wv][2];
        }
        part[b]       = s1;
        part[256 + b] = s2;
        part[512 + b] = s3;
    }
}

// ---------------------------------------------------------------------------
// Final reduce -> scalar loss
// ---------------------------------------------------------------------------
__global__ __launch_bounds__(256) void loss_final_kernel(
    const float* __restrict__ part, float* __restrict__ out)
{
    float a = 0.f;
    for (int i = threadIdx.x; i < 768; i += 256) a += part[i];
#pragma unroll
    for (int o = 32; o >= 1; o >>= 1) a += __shfl_xor(a, o, 64);
    __shared__ float red[4];
    const int wv = threadIdx.x >> 6, ln = threadIdx.x & 63;
    if (ln == 0) red[wv] = a;
    __syncthreads();
    if (threadIdx.x == 0) {
        out[0] = (red[0] + red[1] + red[2] + red[3]) * (1.0f / (float)TOT);
    }
}

extern "C" void kernel_launch(void* const* d_in, const int* in_sizes, int n_in,
                              void* d_out, int out_size, void* d_ws, size_t ws_size,
                              hipStream_t stream)
{
    const float* env   = (const float*)d_in[0];
    const float* state = (const float*)d_in[1];
    const float* w1    = (const float*)d_in[2];
    const float* w2    = (const float*)d_in[3];
    const float* w3    = (const float*)d_in[4];
    float* out = (float*)d_out;
    float* part = (float*)d_ws;    // 768 floats

    hipLaunchKernelGGL(fused_brain_kernel, dim3(256), dim3(1024), 0, stream,
                       env, state, w1, w2, w3, part);
    hipLaunchKernelGGL(loss_final_kernel, dim3(1), dim3(256), 0, stream,
                       part, out);
}